// Round 12
// baseline (505.838 us; speedup 1.0000x reference)
//
#include <hip/hip_runtime.h>
#include <math.h>

#define EMBED    256
#define HIDDEN   512
#define Nn       2000
#define Ee       2000
#define BM       64      // edges per tile
#define TILES    16      // tiles per persistent block
#define NBLK     250     // 250 * 16 * 64 = 256000 edges
#define NTHREADS 512     // 8 waves: 0-3 consumers (MFMA), 4-7 producers (stage)
#define FP       264     // shorts per feat row (256 + 8 pad; measured 0-conflict)

typedef __attribute__((ext_vector_type(8)))  short bf16x8;
typedef __attribute__((ext_vector_type(16))) float f32x16;

static __device__ __forceinline__ short f2bf(float f) {
  unsigned u = __builtin_bit_cast(unsigned, f);
  u += 0x7fffu + ((u >> 16) & 1u);
  return (short)(u >> 16);
}

static __device__ __forceinline__ bf16x8 cvt8(float4 a, float4 b) {
  bf16x8 v;
  v[0]=f2bf(a.x); v[1]=f2bf(a.y); v[2]=f2bf(a.z); v[3]=f2bf(a.w);
  v[4]=f2bf(b.x); v[5]=f2bf(b.y); v[6]=f2bf(b.z); v[7]=f2bf(b.w);
  return v;
}

#define LBAR() do { asm volatile("s_waitcnt lgkmcnt(0)" ::: "memory"); \
                    __builtin_amdgcn_s_barrier(); \
                    asm volatile("" ::: "memory"); } while (0)

// ---- prep: W1 (513x512 f32 [k][n]) -> fragment-major W1F bf16 ----
// W1F[((tn*32 + tk)*64 + lane)*8 + q] = W1[tk*16 + (lane>>5)*8 + q][tn*32 + (lane&31)]
__global__ void w1f_kernel(const float* __restrict__ W1, short* __restrict__ W1F) {
  const int t  = blockIdx.x * 512 + threadIdx.x;   // 32768 fragment-lanes
  const int l  = t & 63;
  const int tk = (t >> 6) & 31;
  const int tn = t >> 11;
  const int n  = tn * 32 + (l & 31);
  const int k0 = tk * 16 + (l >> 5) * 8;
  bf16x8 v;
#pragma unroll
  for (int q = 0; q < 8; ++q)
    v[q] = f2bf(W1[(size_t)(k0 + q) * HIDDEN + n]);
  *(bf16x8*)(W1F + (size_t)t * 8) = v;
}

// ---- main: producer/consumer specialized waves ----
__global__ __launch_bounds__(NTHREADS, 2)
void edge_kernel(const float* __restrict__ emb, const float* __restrict__ locs,
                 const int* __restrict__ edges, const int* __restrict__ dbias,
                 const float* __restrict__ W1, const float* __restrict__ b1,
                 const float* __restrict__ W2, const float* __restrict__ b2,
                 const short* __restrict__ W1F, float* __restrict__ out)
{
  __shared__ short feat[2][BM][FP];               // 67,584 B
  __shared__ float b1_s[HIDDEN], w513_s[HIDDEN], w2_s[HIDDEN];  // 6 KB
  __shared__ float part_s[2][2][BM];              // 1 KB  [tile-parity][ng][edge]
  __shared__ float dist_s[2][BM];
  __shared__ int   valid_s[2][BM];
  __shared__ int   ibase_s[2][BM], jbase_s[2][BM];   // total ~76.8 KB

  const int tid = threadIdx.x;

  // bijective XCD-chunked swizzle over 250 blocks (xcd 0,1 -> 32; 2..7 -> 31)
  const int orig = blockIdx.x;
  const int xcd  = orig & 7;
  const int idx  = orig >> 3;
  const int sbid = (xcd < 2 ? xcd * 32 : 64 + (xcd - 2) * 31) + idx;
  const int eblk = sbid * (TILES * BM);

  b1_s[tid]   = b1[tid];
  w513_s[tid] = W1[(size_t)512 * HIDDEN + tid];
  w2_s[tid]   = W2[tid];
  const float b2s_base = b2[0] + (float)dbias[0];

  const int lane = tid & 63;
  const int w    = tid >> 6;      // wave 0..7
  const int ln31 = lane & 31;
  const int kg   = lane >> 5;

  // producer-local ids
  const int pt  = tid - 256;      // 0..255 for producers
  const int sq  = pt & 7;         // 16B chunk within row-quarter scheme
  const int ehs = (pt >> 3) & 31; // edge within 32-edge round

  auto do_meta = [&](int T) {     // producer wave 4: pt in [0,64)
    const int g  = eblk + T * BM + pt;
    const int b  = g / Ee;
    const int i0 = edges[2 * g];
    const int j0 = edges[2 * g + 1];
    valid_s[T & 1][pt] = (i0 >= 0) && (j0 >= 0);
    const int ib = b * Nn + (i0 < 0 ? 0 : i0);
    const int jb = b * Nn + (j0 < 0 ? 0 : j0);
    ibase_s[T & 1][pt] = ib;
    jbase_s[T & 1][pt] = jb;
    const float dx = locs[2 * (size_t)ib]     - locs[2 * (size_t)jb];
    const float dy = locs[2 * (size_t)ib + 1] - locs[2 * (size_t)jb + 1];
    dist_s[T & 1][pt] = sqrtf(dx * dx + dy * dy);
  };

  // stage one 256-k phase (64 rows) into feat[dst]; producers only (256 thr)
  auto stage = [&](int tps, int sh, int dst) {
#pragma unroll
    for (int r = 0; r < 2; ++r) {
      const int el = r * 32 + ehs;
      const int rb = sh ? jbase_s[tps & 1][el] : ibase_s[tps & 1][el];
      const float* src = emb + (size_t)rb * EMBED + sq * 8;
#pragma unroll
      for (int m = 0; m < 4; ++m) {
        float4 a  = *(const float4*)(src + m * 64);
        float4 b4 = *(const float4*)(src + m * 64 + 4);
        *(bf16x8*)&feat[dst][el][(sq + 8 * m) * 8] = cvt8(a, b4);
      }
    }
  };

  // ---- prologue ----
  if (w == 4) do_meta(0);
  LBAR();
  if (w >= 4) stage(0, 0, 0);     // tile 0, side i -> feat[0]
  LBAR();

  // consumer mapping: wave w<4: eh = w&1 (32-edge half), ng = w>>1 (256-n half)
  const int eh = w & 1;
  const int ng = w >> 1;

  f32x16 acc[8];                  // 8 n-tiles of 32 (consumer waves)
#pragma unroll
  for (int nt = 0; nt < 8; ++nt)
#pragma unroll
    for (int q = 0; q < 16; ++q) acc[nt][q] = 0.f;

  // wa(nt, k16) at W1F + ((ng*8+nt)*32 + k16)*512 + lane*8
  const short* wfb = W1F + (size_t)(ng * 8 * 32) * 512 + lane * 8;

#pragma unroll 1
  for (int p = 0; p < 2 * TILES; ++p) {
    const int bb   = p & 1;
    const int half = p & 1;            // k-half of W1 this phase covers

    if (w < 4) {
      // ---------------- consumer: pure L2-loads + LDS-reads + MFMA ----------
      __builtin_amdgcn_s_setprio(1);
#pragma unroll
      for (int ks = 0; ks < 16; ++ks) {
        bf16x8 fb = *(const bf16x8*)(&feat[bb][eh * 32 + ln31][ks * 16 + kg * 8]);
#pragma unroll
        for (int nt = 0; nt < 8; ++nt) {
          bf16x8 wa = *(const bf16x8*)(wfb + (size_t)(nt * 32 + half * 16 + ks) * 512);
          acc[nt] = __builtin_amdgcn_mfma_f32_32x32x16_bf16(wa, fb, acc[nt], 0, 0, 0);
        }
      }
      __builtin_amdgcn_s_setprio(0);

      if (p & 1) {
        // epilogue for tile t = p>>1 (before barrier, so producers can read
        // part_s next phase)
        const int t   = p >> 1;
        const int par = t & 1;
        const float dv = dist_s[par][eh * 32 + ln31];
        float ps = 0.f;
#pragma unroll
        for (int nt = 0; nt < 8; ++nt) {
#pragma unroll
          for (int r = 0; r < 16; ++r) {
            const int n = ng * 256 + nt * 32 + (r & 3) + ((r >> 2) << 3) + (kg << 2);
            float pv = acc[nt][r] + b1_s[n] + dv * w513_s[n];
            ps += fmaxf(pv, 0.f) * w2_s[n];
          }
        }
        ps += __shfl_xor(ps, 32, 64);       // fold kg halves (rows +4)
        if (lane < 32) part_s[par][ng][eh * 32 + ln31] = ps;
#pragma unroll
        for (int nt = 0; nt < 8; ++nt)
#pragma unroll
          for (int q = 0; q < 16; ++q) acc[nt][q] = 0.f;
      }
    } else {
      // ---------------- producer: all HBM traffic lives here ---------------
      if (p < 2 * TILES - 1)
        stage((p + 1) >> 1, (p + 1) & 1, (p + 1) & 1);
      if (!(p & 1)) {
        const int t = p >> 1;
        if (t >= 1 && pt < BM) {           // store tile t-1 logits
          const int par = (t - 1) & 1;
          float s = part_s[par][0][pt] + part_s[par][1][pt] + b2s_base;
          if (!valid_s[par][pt]) s = -__builtin_inff();
          out[eblk + (t - 1) * BM + pt] = s;
        }
        if (w == 4 && t + 1 < TILES) do_meta(t + 1);
      }
    }
    LBAR();
  }

  // final store: tile TILES-1 (parity 1)
  if (tid < BM) {
    float s = part_s[1][0][tid] + part_s[1][1][tid] + b2s_base;
    if (!valid_s[1][tid]) s = -__builtin_inff();
    out[eblk + (TILES - 1) * BM + tid] = s;
  }
}

extern "C" void kernel_launch(void* const* d_in, const int* in_sizes, int n_in,
                              void* d_out, int out_size, void* d_ws, size_t ws_size,
                              hipStream_t stream) {
  const float* emb   = (const float*)d_in[0];
  const float* locs  = (const float*)d_in[1];
  const int*   edges = (const int*)d_in[2];
  const int*   dbias = (const int*)d_in[3];
  const float* W1    = (const float*)d_in[4];
  const float* b1    = (const float*)d_in[5];
  const float* W2    = (const float*)d_in[6];
  const float* b2    = (const float*)d_in[7];
  float*       out   = (float*)d_out;
  short*       W1F   = (short*)d_ws;   // 512*512*2 = 512 KiB fragment-major

  w1f_kernel<<<dim3(64), dim3(512), 0, stream>>>(W1, W1F);
  edge_kernel<<<dim3(NBLK), dim3(NTHREADS), 0, stream>>>(
      emb, locs, edges, dbias, W1, b1, W2, b2, (const short*)W1F, out);
}

// Round 13
// 176.283 us; speedup vs baseline: 2.8695x; 2.8695x over previous
//
#include <hip/hip_runtime.h>
#include <math.h>

#define EMBED    256
#define HIDDEN   512
#define Nn       2000
#define Ee       2000
#define BM       128     // edges per tile
#define TILES    8       // tiles per persistent block
#define NBLK     250     // 250 * 8 * 128 = 256000 edges
#define NTHREADS 512     // 8 waves; wave w owns n-slice [w*64, +64)
#define FP       72      // shorts per feat row (64 k + 8 pad; measured 0-conflict)

typedef __attribute__((ext_vector_type(8)))  short bf16x8;
typedef __attribute__((ext_vector_type(16))) float f32x16;

static __device__ __forceinline__ short f2bf(float f) {
  unsigned u = __builtin_bit_cast(unsigned, f);
  u += 0x7fffu + ((u >> 16) & 1u);
  return (short)(u >> 16);
}

static __device__ __forceinline__ bf16x8 cvt8(float4 a, float4 b) {
  bf16x8 v;
  v[0]=f2bf(a.x); v[1]=f2bf(a.y); v[2]=f2bf(a.z); v[3]=f2bf(a.w);
  v[4]=f2bf(b.x); v[5]=f2bf(b.y); v[6]=f2bf(b.z); v[7]=f2bf(b.w);
  return v;
}

#define LBAR() do { asm volatile("s_waitcnt lgkmcnt(0)" ::: "memory"); \
                    __builtin_amdgcn_s_barrier(); \
                    asm volatile("" ::: "memory"); } while (0)

// ---- prep: W1 (513x512 f32 [k][n]) -> fragment-major W1F bf16 ----
// W1F[((tn*32 + tk)*64 + lane)*8 + q] = W1[tk*16 + (lane>>5)*8 + q][tn*32 + (lane&31)]
__global__ void w1f_kernel(const float* __restrict__ W1, short* __restrict__ W1F) {
  const int t  = blockIdx.x * 512 + threadIdx.x;   // 32768 fragment-lanes
  const int l  = t & 63;
  const int tk = (t >> 6) & 31;
  const int tn = t >> 11;
  const int n  = tn * 32 + (l & 31);
  const int k0 = tk * 16 + (l >> 5) * 8;
  bf16x8 v;
#pragma unroll
  for (int q = 0; q < 8; ++q)
    v[q] = f2bf(W1[(size_t)(k0 + q) * HIDDEN + n]);
  *(bf16x8*)(W1F + (size_t)t * 8) = v;
}

// ---- main: 64-k phases; W1F slice staged to LDS (shared); feat dbuf ----
__global__ __launch_bounds__(NTHREADS, 2)
void edge_kernel(const float* __restrict__ emb, const float* __restrict__ locs,
                 const int* __restrict__ edges, const int* __restrict__ dbias,
                 const float* __restrict__ W1, const float* __restrict__ b1,
                 const float* __restrict__ W2, const float* __restrict__ b2,
                 const short* __restrict__ W1F, float* __restrict__ out)
{
  __shared__ short wlds[64 * 512];        // 65,536 B: 64 frag-groups x 1 KB
  __shared__ short feat[2][BM][FP];       // 36,864 B
  __shared__ float b1_s[HIDDEN], w513_s[HIDDEN], w2_s[HIDDEN];  // 6 KB
  __shared__ float part_s[8][BM];         // 4 KB
  __shared__ float dist_s[2][BM];
  __shared__ int   valid_s[2][BM];
  __shared__ int   ibase_s[2][BM], jbase_s[2][BM];   // total ~114 KB

  const int tid = threadIdx.x;

  // bijective XCD-chunked swizzle over 250 blocks (xcd 0,1 -> 32; 2..7 -> 31)
  const int orig = blockIdx.x;
  const int xcd  = orig & 7;
  const int idx  = orig >> 3;
  const int sbid = (xcd < 2 ? xcd * 32 : 64 + (xcd - 2) * 31) + idx;
  const int eblk = sbid * (TILES * BM);

  b1_s[tid]   = b1[tid];
  w513_s[tid] = W1[(size_t)512 * HIDDEN + tid];
  w2_s[tid]   = W2[tid];
  const float b2s_base = b2[0] + (float)dbias[0];

  auto do_meta = [&](int T) {     // tid < BM only
    const int g  = eblk + T * BM + tid;
    const int b  = g / Ee;
    const int i0 = edges[2 * g];
    const int j0 = edges[2 * g + 1];
    valid_s[T & 1][tid] = (i0 >= 0) && (j0 >= 0);
    const int ib = b * Nn + (i0 < 0 ? 0 : i0);
    const int jb = b * Nn + (j0 < 0 ? 0 : j0);
    ibase_s[T & 1][tid] = ib;
    jbase_s[T & 1][tid] = jb;
    const float dx = locs[2 * (size_t)ib]     - locs[2 * (size_t)jb];
    const float dy = locs[2 * (size_t)ib + 1] - locs[2 * (size_t)jb + 1];
    dist_s[T & 1][tid] = sqrtf(dx * dx + dy * dy);
  };

  // staging maps
  const int sub = tid & 7;        // wlds: sub-chunk within 1 KB group
  const int grp = tid >> 3;       // wlds: fragment group 0..63 (tn=grp>>2, tk4=grp&3)
  const int e   = tid >> 2;       // feat: edge 0..127
  const int sq  = tid & 3;        // feat: 16-float quarter of the 64-k row

  const int lane = tid & 63;
  const int w    = tid >> 6;      // wave 0..7 -> n-slice [w*64, +64)
  const int ln31 = lane & 31;
  const int kg   = lane >> 5;

  if (tid < BM) do_meta(0);
  LBAR();

  // ---- prologue: stage wlds slice (side0,q0) + feat (tile0,side0,q0) ----
  {
    const int F = (grp >> 2) * 32 + (grp & 3);     // side=0, q=0
    bf16x8 wr[8];
#pragma unroll
    for (int i = 0; i < 8; ++i)
      wr[i] = *(const bf16x8*)(W1F + (size_t)F * 512 + (sub + 8 * i) * 8);
    const float* src = emb + (size_t)ibase_s[0][e] * EMBED + sq * 16;
    float4 g0 = *(const float4*)(src);
    float4 g1 = *(const float4*)(src + 4);
    float4 g2 = *(const float4*)(src + 8);
    float4 g3 = *(const float4*)(src + 12);
#pragma unroll
    for (int i = 0; i < 8; ++i)
      *(bf16x8*)&wlds[grp * 512 + (sub + 8 * i) * 8] = wr[i];
    *(bf16x8*)&feat[0][e][sq * 16]     = cvt8(g0, g1);
    *(bf16x8*)&feat[0][e][sq * 16 + 8] = cvt8(g2, g3);
  }
  LBAR();

  f32x16 acc[4][2];               // [et][nt]
#pragma unroll
  for (int et = 0; et < 4; ++et)
#pragma unroll
    for (int nt = 0; nt < 2; ++nt)
#pragma unroll
      for (int q = 0; q < 16; ++q) acc[et][nt][q] = 0.f;

  const int waoff0 = ((w * 2 + 0) * 4) * 512 + lane * 8;   // + ks*512
  const int waoff1 = ((w * 2 + 1) * 4) * 512 + lane * 8;

#pragma unroll 1
  for (int p = 0; p < 8 * TILES; ++p) {
    const int tile = p >> 3;
    const int ph8  = p & 7;
    const int bb   = p & 1;
    const int nb   = bb ^ 1;
    const bool more = (p < 8 * TILES - 1);

    // ---- A: issue next-phase staging loads (held in regs across compute) ----
    bf16x8 wr[8];
    float4 gr0, gr1, gr2, gr3;
    if (more) {
      const int pn   = p + 1;
      const int ph8n = pn & 7;
      const int sn   = ph8n >> 2;           // side of W1 k-range
      const int qn   = ph8n & 3;            // 64-k quarter within side
      const int tn_  = pn >> 3;
      const int F = (grp >> 2) * 32 + sn * 16 + qn * 4 + (grp & 3);
#pragma unroll
      for (int i = 0; i < 8; ++i)
        wr[i] = *(const bf16x8*)(W1F + (size_t)F * 512 + (sub + 8 * i) * 8);
      const int* mb = sn ? jbase_s[tn_ & 1] : ibase_s[tn_ & 1];
      const float* src = emb + (size_t)mb[e] * EMBED + qn * 64 + sq * 16;
      gr0 = *(const float4*)(src);
      gr1 = *(const float4*)(src + 4);
      gr2 = *(const float4*)(src + 8);
      gr3 = *(const float4*)(src + 12);
    }

    // ---- C: compute 4 k-steps (wa from wlds, fb from feat[bb]) ----
#pragma unroll
    for (int ks = 0; ks < 4; ++ks) {
      bf16x8 wa0 = *(const bf16x8*)&wlds[waoff0 + ks * 512];
      bf16x8 wa1 = *(const bf16x8*)&wlds[waoff1 + ks * 512];
      __builtin_amdgcn_s_setprio(1);
#pragma unroll
      for (int et = 0; et < 4; ++et) {
        bf16x8 fb = *(const bf16x8*)(&feat[bb][et * 32 + ln31][ks * 16 + kg * 8]);
        acc[et][0] = __builtin_amdgcn_mfma_f32_32x32x16_bf16(wa0, fb, acc[et][0], 0, 0, 0);
        acc[et][1] = __builtin_amdgcn_mfma_f32_32x32x16_bf16(wa1, fb, acc[et][1], 0, 0, 0);
      }
      __builtin_amdgcn_s_setprio(0);
    }

    // meta for next tile (placed after compute so its vmem waits don't
    // force-drain this phase's staging loads before C)
    if (ph8 == 0 && tile + 1 < TILES && tid < BM) do_meta(tile + 1);

    LBAR();   // D: all wlds/feat[bb] reads complete block-wide

    // ---- E: land staged data (wlds overwrite + feat[nb]) ----
    if (more) {
#pragma unroll
      for (int i = 0; i < 8; ++i)
        *(bf16x8*)&wlds[grp * 512 + (sub + 8 * i) * 8] = wr[i];
      *(bf16x8*)&feat[nb][e][sq * 16]     = cvt8(gr0, gr1);
      *(bf16x8*)&feat[nb][e][sq * 16 + 8] = cvt8(gr2, gr3);
    }
    LBAR();   // F: writes visible for next phase

    // ---- tile epilogue ----
    if (ph8 == 7) {
      const int par = tile & 1;
      float dv[4], ps[4];
#pragma unroll
      for (int et = 0; et < 4; ++et) {
        dv[et] = dist_s[par][et * 32 + ln31];
        ps[et] = 0.f;
      }
#pragma unroll
      for (int nt = 0; nt < 2; ++nt) {
#pragma unroll
        for (int r = 0; r < 16; ++r) {
          const int n = w * 64 + nt * 32 + (r & 3) + ((r >> 2) << 3) + (kg << 2);
          const float bias = b1_s[n];
          const float wd   = w513_s[n];
          const float w2v  = w2_s[n];
#pragma unroll
          for (int et = 0; et < 4; ++et) {
            float pv = acc[et][nt][r] + bias + dv[et] * wd;
            ps[et] += fmaxf(pv, 0.f) * w2v;
          }
        }
      }
#pragma unroll
      for (int et = 0; et < 4; ++et) ps[et] += __shfl_xor(ps[et], 32, 64);
      if (lane < 32) {
#pragma unroll
        for (int et = 0; et < 4; ++et) part_s[w][et * 32 + ln31] = ps[et];
      }
      LBAR();
      if (tid < BM) {
        float s = 0.f;
#pragma unroll
        for (int wv = 0; wv < 8; ++wv) s += part_s[wv][tid];
        float logit = s + b2s_base;
        if (!valid_s[par][tid]) logit = -__builtin_inff();
        out[eblk + tile * BM + tid] = logit;
      }
#pragma unroll
      for (int et = 0; et < 4; ++et)
#pragma unroll
        for (int nt = 0; nt < 2; ++nt)
#pragma unroll
          for (int q = 0; q < 16; ++q) acc[et][nt][q] = 0.f;
    }
  }
}

extern "C" void kernel_launch(void* const* d_in, const int* in_sizes, int n_in,
                              void* d_out, int out_size, void* d_ws, size_t ws_size,
                              hipStream_t stream) {
  const float* emb   = (const float*)d_in[0];
  const float* locs  = (const float*)d_in[1];
  const int*   edges = (const int*)d_in[2];
  const int*   dbias = (const int*)d_in[3];
  const float* W1    = (const float*)d_in[4];
  const float* b1    = (const float*)d_in[5];
  const float* W2    = (const float*)d_in[6];
  const float* b2    = (const float*)d_in[7];
  float*       out   = (float*)d_out;
  short*       W1F   = (short*)d_ws;   // 512*512*2 = 512 KiB fragment-major

  w1f_kernel<<<dim3(64), dim3(512), 0, stream>>>(W1, W1F);
  edge_kernel<<<dim3(NBLK), dim3(NTHREADS), 0, stream>>>(
      emb, locs, edges, dbias, W1, b1, W2, b2, (const short*)W1F, out);
}